// Round 9
// baseline (289.649 us; speedup 1.0000x reference)
//
#include <hip/hip_runtime.h>

#define D_IN    784
#define HDIM    512
#define BATCH_N 1024
#define TC      4

#define WT_FLOATS   ((size_t)D_IN * HDIM)        // 401408 elements
#define CKPT_STRIDE ((size_t)BATCH_N * HDIM)     // 524288 floats per slot

typedef unsigned short ushort_t;
typedef unsigned int   uint_t;

__device__ __forceinline__ float relu_(float v) { return fmaxf(v, 0.0f); }
__device__ __forceinline__ float sigmoid_(float v) {
    return __builtin_amdgcn_rcpf(1.0f + __expf(-v));
}
__device__ __forceinline__ ushort_t f2bf(float v) {   // RNE, matches HW bf16 cvt
    uint_t u = __float_as_uint(v);
    return (ushort_t)((u + 0x7fffu + ((u >> 16) & 1u)) >> 16);
}
__device__ __forceinline__ void unpack8(uint4 u, float f[8]) {
    f[0] = __uint_as_float(u.x << 16); f[1] = __uint_as_float(u.x & 0xffff0000u);
    f[2] = __uint_as_float(u.y << 16); f[3] = __uint_as_float(u.y & 0xffff0000u);
    f[4] = __uint_as_float(u.z << 16); f[5] = __uint_as_float(u.z & 0xffff0000u);
    f[6] = __uint_as_float(u.w << 16); f[7] = __uint_as_float(u.w & 0xffff0000u);
}

// ---------------------------------------------------------------------------
// Pass 0a: hWb[i] = bf16(hW[i])   (layout already [D][H])
// ---------------------------------------------------------------------------
__global__ __launch_bounds__(256, 4)
void cast_hW(const float* __restrict__ hW, ushort_t* __restrict__ hWb) {
    int idx = blockIdx.x * 256 + threadIdx.x;
    if (idx < (int)(D_IN * HDIM)) hWb[idx] = f2bf(hW[idx]);
}

// ---------------------------------------------------------------------------
// Pass 0b: LDS-tiled transpose+cast in_W [H][D] fp32 -> wTb [D][H] bf16
// ---------------------------------------------------------------------------
__global__ __launch_bounds__(256, 2)
void transpose_cast_inW(const float* __restrict__ inW, ushort_t* __restrict__ wTb) {
    __shared__ float tile[32][33];
    const int ti = blockIdx.x * 32;
    const int th = blockIdx.y * 32;
    const int lx = threadIdx.x & 31;
    const int ly = threadIdx.x >> 5;
    #pragma unroll
    for (int rr = 0; rr < 4; ++rr) {
        int h = th + ly + rr * 8;
        int i = ti + lx;
        float v = (i < D_IN) ? inW[(size_t)h * D_IN + i] : 0.0f;
        tile[ly + rr * 8][lx] = v;
    }
    __syncthreads();
    #pragma unroll
    for (int rr = 0; rr < 4; ++rr) {
        int i = ti + ly + rr * 8;
        if (i < D_IN) wTb[(size_t)i * HDIM + th + lx] = f2bf(tile[lx][ly + rr * 8]);
    }
}

// ---------------------------------------------------------------------------
// Pass 1: G[k][b][h] = sum_{i in seg k} x[b,i]*wTb[i][h]  -> ckpt slot k+1
// Thread owns 16 contiguous h (hc*16..+15) for 2 rows.
// ---------------------------------------------------------------------------
__global__ __launch_bounds__(256, 4)
void seg_sums(const float* __restrict__ x, const ushort_t* __restrict__ wTb,
              float* __restrict__ ckpt, int seglen) {
    const int rt = blockIdx.x;
    const int k  = blockIdx.y;
    const int tid = threadIdx.x;
    const int r2 = tid >> 5;
    const int hc = tid & 31;
    const int r0 = rt * 16 + r2;
    const int r1 = r0 + 8;
    const int i0 = k * seglen;

    float acc0[16], acc1[16];
    #pragma unroll
    for (int j = 0; j < 16; ++j) { acc0[j] = 0.0f; acc1[j] = 0.0f; }

    const float* x0 = x + (size_t)r0 * D_IN + i0;
    const float* x1 = x + (size_t)r1 * D_IN + i0;
    const ushort_t* w = wTb + (size_t)i0 * HDIM + hc * 16;

    for (int i = 0; i < seglen; ++i) {
        const float xa = x0[i];
        const float xb = x1[i];
        const ushort_t* wr = w + (size_t)i * HDIM;
        uint4 u0 = *(const uint4*)(wr);
        uint4 u1 = *(const uint4*)(wr + 8);
        float wf[16];
        unpack8(u0, wf);
        unpack8(u1, wf + 8);
        #pragma unroll
        for (int j = 0; j < 16; ++j) {
            acc0[j] = fmaf(xa, wf[j], acc0[j]);
            acc1[j] = fmaf(xb, wf[j], acc1[j]);
        }
    }

    float* g0 = ckpt + (size_t)(k + 1) * CKPT_STRIDE + (size_t)r0 * HDIM + hc * 16;
    float* g1 = ckpt + (size_t)(k + 1) * CKPT_STRIDE + (size_t)r1 * HDIM + hc * 16;
    #pragma unroll
    for (int j = 0; j < 4; ++j) {
        *(float4*)(g0 + 4 * j) = make_float4(acc0[4*j+0], acc0[4*j+1], acc0[4*j+2], acc0[4*j+3]);
        *(float4*)(g1 + 4 * j) = make_float4(acc1[4*j+0], acc1[4*j+1], acc1[4*j+2], acc1[4*j+3]);
    }
}

// ---------------------------------------------------------------------------
// Pass 1.5: ckpt[0]=in_b ; ckpt[k] = ckpt[k-1] + G[k-1]
// ---------------------------------------------------------------------------
__global__ __launch_bounds__(256, 4)
void prefix_ck(const float* __restrict__ in_b, float* __restrict__ ckpt, int nseg) {
    int idx = blockIdx.x * 256 + threadIdx.x;
    int b  = idx >> 7;
    int hq = idx & 127;
    float* p = ckpt + (size_t)b * HDIM + hq * 4;
    float4 cur = *(const float4*)(in_b + hq * 4);
    *(float4*)p = cur;
    for (int k = 1; k < nseg; ++k) {
        float4 g = *(const float4*)(p + (size_t)k * CKPT_STRIDE);
        cur.x += g.x; cur.y += g.y; cur.z += g.z; cur.w += g.w;
        *(float4*)(p + (size_t)k * CKPT_STRIDE) = cur;
    }
}

// ---------------------------------------------------------------------------
// Pass 2: segment scan, bf16 staged weights.
// Block = 4 waves (256 thr); wave owns 4 batch rows. Lane l owns h=8l..8l+7.
// Prefetch issued AFTER the barrier (full-chunk latency cover).
// Single-pass LDS-transpose reduction: 16 outputs, 4 lanes each.
// ---------------------------------------------------------------------------
__global__ __launch_bounds__(256, 4)
void nade_fwd6(const float* __restrict__ x,
               const float* __restrict__ ckpt,
               const ushort_t* __restrict__ hWb,
               const float* __restrict__ h_b,
               const ushort_t* __restrict__ wTb,
               float* __restrict__ out,
               int seglen, int nch) {
    __shared__ ushort_t sbuf[2][2][TC * HDIM];   // [buf][mat][2048] = 16 KB
    __shared__ float    sred[4][16 * 68];        // 17.4 KB

    const int tid = threadIdx.x;
    const int w   = tid >> 6;                    // wave 0..3
    const int l   = tid & 63;
    const int k   = blockIdx.y;
    const int base = k * seglen;
    const int row0 = blockIdx.x * 16 + w * 4;

    // accumulators from checkpoint k; lane owns h = 8l..8l+7
    float a[4][8];
    #pragma unroll
    for (int r = 0; r < 4; ++r) {
        const float* ap = ckpt + (size_t)k * CKPT_STRIDE + (size_t)(row0 + r) * HDIM + 8 * l;
        float4 a0 = *(const float4*)(ap);
        float4 a1 = *(const float4*)(ap + 4);
        a[r][0]=a0.x; a[r][1]=a0.y; a[r][2]=a0.z; a[r][3]=a0.w;
        a[r][4]=a1.x; a[r][5]=a1.y; a[r][6]=a1.z; a[r][7]=a1.w;
    }

    // x bitmasks (x exactly 0/1), wave-uniform
    unsigned long long lo0, lo1, lo2, lo3;
    unsigned long long hi0 = 0, hi1 = 0, hi2 = 0, hi3 = 0;
    {
        const float* xr0 = x + (size_t)(row0 + 0) * D_IN + base;
        const float* xr1 = x + (size_t)(row0 + 1) * D_IN + base;
        const float* xr2 = x + (size_t)(row0 + 2) * D_IN + base;
        const float* xr3 = x + (size_t)(row0 + 3) * D_IN + base;
        float v;
        v = (l < seglen) ? xr0[l] : 0.0f; lo0 = __ballot(v != 0.0f);
        v = (l < seglen) ? xr1[l] : 0.0f; lo1 = __ballot(v != 0.0f);
        v = (l < seglen) ? xr2[l] : 0.0f; lo2 = __ballot(v != 0.0f);
        v = (l < seglen) ? xr3[l] : 0.0f; lo3 = __ballot(v != 0.0f);
        if (seglen > 64) {
            v = (64 + l < seglen) ? xr0[64 + l] : 0.0f; hi0 = __ballot(v != 0.0f);
            v = (64 + l < seglen) ? xr1[64 + l] : 0.0f; hi1 = __ballot(v != 0.0f);
            v = (64 + l < seglen) ? xr2[64 + l] : 0.0f; hi2 = __ballot(v != 0.0f);
            v = (64 + l < seglen) ? xr3[64 + l] : 0.0f; hi3 = __ballot(v != 0.0f);
        }
    }

    // reduction/output geometry: output o = l>>2 -> row r=l>>4, t=(l>>2)&3
    const int tsel = (l >> 2) & 3;
    float* optr = out + (size_t)(row0 + (l >> 4)) * D_IN + base + tsel;

    // wave w stages mat m=w>>1, half hf=w&1 : 2 x 1KB global_load_lds issues
#define STAGE6(buf_, c_) {                                                                  \
        const int m_  = w >> 1;                                                             \
        const int hf_ = w & 1;                                                              \
        const ushort_t* src_ = (m_ ? wTb : hWb) + (size_t)(base + (c_) * TC) * HDIM         \
                               + hf_ * 1024 + l * 8;                                        \
        ushort_t* dst_ = &sbuf[buf_][m_][hf_ * 1024 + l * 8];                               \
        __builtin_amdgcn_global_load_lds(                                                   \
            (const __attribute__((address_space(1))) void*)(src_),                          \
            (__attribute__((address_space(3))) void*)(dst_), 16, 0, 0);                     \
        __builtin_amdgcn_global_load_lds(                                                   \
            (const __attribute__((address_space(1))) void*)(src_ + 512),                    \
            (__attribute__((address_space(3))) void*)(dst_ + 512), 16, 0, 0);               \
    }

    STAGE6(0, 0);
    if (nch > 1) STAGE6(1, 1);
    __syncthreads();    // drains both prologue stages

    for (int c = 0; c < nch; ++c) {
        const int buf = c & 1;
        const int sh = c * TC;
        const int s2 = sh & 63;
        const unsigned b0 = (unsigned)((((sh >= 64) ? hi0 : lo0) >> s2) & 15ull);
        const unsigned b1 = (unsigned)((((sh >= 64) ? hi1 : lo1) >> s2) & 15ull);
        const unsigned b2 = (unsigned)((((sh >= 64) ? hi2 : lo2) >> s2) & 15ull);
        const unsigned b3 = (unsigned)((((sh >= 64) ? hi3 : lo3) >> s2) & 15ull);
        const unsigned bu = b0 | b1 | b2 | b3;

        float4 hbc = *(const float4*)(h_b + base + sh);

        float part[4][4];
        #pragma unroll
        for (int t = 0; t < TC; ++t) {
            uint4 hv = *(const uint4*)&sbuf[buf][0][t * 512 + 8 * l];
            float hf[8];
            unpack8(hv, hf);
            #pragma unroll
            for (int r = 0; r < 4; ++r) {
                float p = relu_(a[r][0]) * hf[0];
                p = fmaf(relu_(a[r][1]), hf[1], p);
                p = fmaf(relu_(a[r][2]), hf[2], p);
                p = fmaf(relu_(a[r][3]), hf[3], p);
                p = fmaf(relu_(a[r][4]), hf[4], p);
                p = fmaf(relu_(a[r][5]), hf[5], p);
                p = fmaf(relu_(a[r][6]), hf[6], p);
                p = fmaf(relu_(a[r][7]), hf[7], p);
                part[r][t] = p;
            }

            const unsigned bt = 1u << t;
            if (bu & bt) {                 // wave-uniform
                uint4 wv = *(const uint4*)&sbuf[buf][1][t * 512 + 8 * l];
                float wf[8];
                unpack8(wv, wf);
                if (b0 & bt) {
                    a[0][0]+=wf[0]; a[0][1]+=wf[1]; a[0][2]+=wf[2]; a[0][3]+=wf[3];
                    a[0][4]+=wf[4]; a[0][5]+=wf[5]; a[0][6]+=wf[6]; a[0][7]+=wf[7];
                }
                if (b1 & bt) {
                    a[1][0]+=wf[0]; a[1][1]+=wf[1]; a[1][2]+=wf[2]; a[1][3]+=wf[3];
                    a[1][4]+=wf[4]; a[1][5]+=wf[5]; a[1][6]+=wf[6]; a[1][7]+=wf[7];
                }
                if (b2 & bt) {
                    a[2][0]+=wf[0]; a[2][1]+=wf[1]; a[2][2]+=wf[2]; a[2][3]+=wf[3];
                    a[2][4]+=wf[4]; a[2][5]+=wf[5]; a[2][6]+=wf[6]; a[2][7]+=wf[7];
                }
                if (b3 & bt) {
                    a[3][0]+=wf[0]; a[3][1]+=wf[1]; a[3][2]+=wf[2]; a[3][3]+=wf[3];
                    a[3][4]+=wf[4]; a[3][5]+=wf[5]; a[3][6]+=wf[6]; a[3][7]+=wf[7];
                }
            }
        }

        // single-pass reduction: 16 writes, 4 b128 reads, 2 narrow shfl
        #pragma unroll
        for (int r = 0; r < 4; ++r) {
            #pragma unroll
            for (int t = 0; t < TC; ++t)
                sred[w][(r * 4 + t) * 68 + l] = part[r][t];
        }

        const float* pr = &sred[w][(l >> 2) * 68 + (l & 3) * 16];
        float4 q0 = *(const float4*)(pr);
        float4 q1 = *(const float4*)(pr + 4);
        float4 q2 = *(const float4*)(pr + 8);
        float4 q3 = *(const float4*)(pr + 12);
        float v = (((q0.x + q0.y) + (q0.z + q0.w)) + ((q1.x + q1.y) + (q1.z + q1.w)))
                + (((q2.x + q2.y) + (q2.z + q2.w)) + ((q3.x + q3.y) + (q3.z + q3.w)));
        v += __shfl_xor(v, 1, 64);
        v += __shfl_xor(v, 2, 64);
        const float hbt = (tsel & 2) ? ((tsel & 1) ? hbc.w : hbc.z)
                                     : ((tsel & 1) ? hbc.y : hbc.x);
        float sv = sigmoid_(v + hbt);
        if ((l & 3) == 0) optr[sh] = sv;

        __syncthreads();
        if (c + 2 < nch) STAGE6(buf, c + 2);   // prefetch AFTER barrier: full-chunk cover
    }
#undef STAGE6
}

// ---------------------------------------------------------------------------
// Fallback (tiny ws): fp32, no workspace use
// ---------------------------------------------------------------------------
__global__ __launch_bounds__(64, 1)
void nade_fwd_fallback(const float* __restrict__ x,
                       const float* __restrict__ in_W,
                       const float* __restrict__ in_b,
                       const float* __restrict__ hW,
                       const float* __restrict__ h_b,
                       float* __restrict__ out) {
    const int b  = blockIdx.x;
    const int l  = threadIdx.x;
    const int h0 = l * 8;

    float a[8];
    {
        float4 b0 = *(const float4*)(in_b + h0);
        float4 b1 = *(const float4*)(in_b + h0 + 4);
        a[0]=b0.x; a[1]=b0.y; a[2]=b0.z; a[3]=b0.w;
        a[4]=b1.x; a[5]=b1.y; a[6]=b1.z; a[7]=b1.w;
    }
    const float* xrow = x + (size_t)b * D_IN;
    float* orow = out + (size_t)b * D_IN;

    for (int i = 0; i < D_IN; ++i) {
        const float4 hw0 = *(const float4*)(hW + (size_t)i * HDIM + h0);
        const float4 hw1 = *(const float4*)(hW + (size_t)i * HDIM + h0 + 4);
        float p;
        p = relu_(a[0]) * hw0.x;
        p = fmaf(relu_(a[1]), hw0.y, p);
        p = fmaf(relu_(a[2]), hw0.z, p);
        p = fmaf(relu_(a[3]), hw0.w, p);
        p = fmaf(relu_(a[4]), hw1.x, p);
        p = fmaf(relu_(a[5]), hw1.y, p);
        p = fmaf(relu_(a[6]), hw1.z, p);
        p = fmaf(relu_(a[7]), hw1.w, p);
        #pragma unroll
        for (int s = 1; s < 64; s <<= 1) p += __shfl_xor(p, s, 64);
        if (l == 0) orow[i] = sigmoid_(p + h_b[i]);

        const float xi = xrow[i];
        if (xi != 0.0f) {
            a[0] = fmaf(xi, in_W[(size_t)(h0+0)*D_IN + i], a[0]);
            a[1] = fmaf(xi, in_W[(size_t)(h0+1)*D_IN + i], a[1]);
            a[2] = fmaf(xi, in_W[(size_t)(h0+2)*D_IN + i], a[2]);
            a[3] = fmaf(xi, in_W[(size_t)(h0+3)*D_IN + i], a[3]);
            a[4] = fmaf(xi, in_W[(size_t)(h0+4)*D_IN + i], a[4]);
            a[5] = fmaf(xi, in_W[(size_t)(h0+5)*D_IN + i], a[5]);
            a[6] = fmaf(xi, in_W[(size_t)(h0+6)*D_IN + i], a[6]);
            a[7] = fmaf(xi, in_W[(size_t)(h0+7)*D_IN + i], a[7]);
        }
    }
}

extern "C" void kernel_launch(void* const* d_in, const int* in_sizes, int n_in,
                              void* d_out, int out_size, void* d_ws, size_t ws_size,
                              hipStream_t stream) {
    const float* x    = (const float*)d_in[0];
    const float* in_W = (const float*)d_in[1];
    const float* in_b = (const float*)d_in[2];
    const float* hW   = (const float*)d_in[3];
    const float* h_b  = (const float*)d_in[4];
    float* out = (float*)d_out;

    // ws layout: wTb (bf16) | hWb (bf16) | ckpt (fp32, nseg slots)
    const size_t bf_bytes = 2 * WT_FLOATS * sizeof(ushort_t);   // 1.6 MB
    int nseg = 0;
    const size_t need14 = bf_bytes + 14 * CKPT_STRIDE * sizeof(float);
    const size_t need7  = bf_bytes +  7 * CKPT_STRIDE * sizeof(float);
    if      (ws_size >= need14) nseg = 14;
    else if (ws_size >= need7)  nseg = 7;

    if (nseg) {
        const int seglen = D_IN / nseg;
        ushort_t* wTb = (ushort_t*)d_ws;
        ushort_t* hWb = wTb + WT_FLOATS;
        float*    ckpt = (float*)(hWb + WT_FLOATS);

        hipLaunchKernelGGL(cast_hW,
                           dim3((D_IN * HDIM + 255) / 256), dim3(256), 0, stream,
                           hW, hWb);
        hipLaunchKernelGGL(transpose_cast_inW,
                           dim3((D_IN + 31) / 32, HDIM / 32), dim3(256), 0, stream,
                           in_W, wTb);
        hipLaunchKernelGGL(seg_sums,
                           dim3(BATCH_N / 16, nseg - 1), dim3(256), 0, stream,
                           x, wTb, ckpt, seglen);
        hipLaunchKernelGGL(prefix_ck,
                           dim3(BATCH_N * (HDIM / 4) / 256), dim3(256), 0, stream,
                           in_b, ckpt, nseg);
        hipLaunchKernelGGL(nade_fwd6,
                           dim3(BATCH_N / 16, nseg), dim3(256), 0, stream,
                           x, ckpt, hWb, h_b, wTb, out, seglen, seglen / TC);
    } else {
        hipLaunchKernelGGL(nade_fwd_fallback,
                           dim3(BATCH_N), dim3(64), 0, stream,
                           x, in_W, in_b, hW, h_b, out);
    }
}

// Round 10
// 139.314 us; speedup vs baseline: 2.0791x; 2.0791x over previous
//
#include <hip/hip_runtime.h>

#define D_IN    784
#define HDIM    512
#define BATCH_N 1024
#define TC      4

#define WT_FLOATS   ((size_t)D_IN * HDIM)        // 401408 elements
#define CKPT_STRIDE ((size_t)BATCH_N * HDIM)     // 524288 floats per slot

typedef unsigned short ushort_t;
typedef unsigned int   uint_t;

__device__ __forceinline__ float relu_(float v) { return fmaxf(v, 0.0f); }
__device__ __forceinline__ float sigmoid_(float v) {
    return __builtin_amdgcn_rcpf(1.0f + __expf(-v));
}
__device__ __forceinline__ ushort_t f2bf(float v) {   // RNE, matches HW bf16 cvt
    uint_t u = __float_as_uint(v);
    return (ushort_t)((u + 0x7fffu + ((u >> 16) & 1u)) >> 16);
}
__device__ __forceinline__ void unpack8(uint4 u, float f[8]) {
    f[0] = __uint_as_float(u.x << 16); f[1] = __uint_as_float(u.x & 0xffff0000u);
    f[2] = __uint_as_float(u.y << 16); f[3] = __uint_as_float(u.y & 0xffff0000u);
    f[4] = __uint_as_float(u.z << 16); f[5] = __uint_as_float(u.z & 0xffff0000u);
    f[6] = __uint_as_float(u.w << 16); f[7] = __uint_as_float(u.w & 0xffff0000u);
}

// ---------------------------------------------------------------------------
// Pass 0a: hWb[i] = bf16(hW[i])   (layout already [D][H])
// ---------------------------------------------------------------------------
__global__ __launch_bounds__(256, 2)
void cast_hW(const float* __restrict__ hW, ushort_t* __restrict__ hWb) {
    int idx = blockIdx.x * 256 + threadIdx.x;
    if (idx < (int)(D_IN * HDIM)) hWb[idx] = f2bf(hW[idx]);
}

// ---------------------------------------------------------------------------
// Pass 0b: LDS-tiled transpose+cast in_W [H][D] fp32 -> wTb [D][H] bf16
// ---------------------------------------------------------------------------
__global__ __launch_bounds__(256, 2)
void transpose_cast_inW(const float* __restrict__ inW, ushort_t* __restrict__ wTb) {
    __shared__ float tile[32][33];
    const int ti = blockIdx.x * 32;
    const int th = blockIdx.y * 32;
    const int lx = threadIdx.x & 31;
    const int ly = threadIdx.x >> 5;
    #pragma unroll
    for (int rr = 0; rr < 4; ++rr) {
        int h = th + ly + rr * 8;
        int i = ti + lx;
        float v = (i < D_IN) ? inW[(size_t)h * D_IN + i] : 0.0f;
        tile[ly + rr * 8][lx] = v;
    }
    __syncthreads();
    #pragma unroll
    for (int rr = 0; rr < 4; ++rr) {
        int i = ti + ly + rr * 8;
        if (i < D_IN) wTb[(size_t)i * HDIM + th + lx] = f2bf(tile[lx][ly + rr * 8]);
    }
}

// ---------------------------------------------------------------------------
// Pass 1: G[k][b][h] = sum_{i in seg k} x[b,i]*wTb[i][h]  -> ckpt slot k+1
// Thread owns 16 contiguous h (hc*16..+15) for 2 rows.
// ---------------------------------------------------------------------------
__global__ __launch_bounds__(256, 2)
void seg_sums(const float* __restrict__ x, const ushort_t* __restrict__ wTb,
              float* __restrict__ ckpt, int seglen) {
    const int rt = blockIdx.x;
    const int k  = blockIdx.y;
    const int tid = threadIdx.x;
    const int r2 = tid >> 5;
    const int hc = tid & 31;
    const int r0 = rt * 16 + r2;
    const int r1 = r0 + 8;
    const int i0 = k * seglen;

    float acc0[16], acc1[16];
    #pragma unroll
    for (int j = 0; j < 16; ++j) { acc0[j] = 0.0f; acc1[j] = 0.0f; }

    const float* x0 = x + (size_t)r0 * D_IN + i0;
    const float* x1 = x + (size_t)r1 * D_IN + i0;
    const ushort_t* w = wTb + (size_t)i0 * HDIM + hc * 16;

    for (int i = 0; i < seglen; ++i) {
        const float xa = x0[i];
        const float xb = x1[i];
        const ushort_t* wr = w + (size_t)i * HDIM;
        uint4 u0 = *(const uint4*)(wr);
        uint4 u1 = *(const uint4*)(wr + 8);
        float wf[16];
        unpack8(u0, wf);
        unpack8(u1, wf + 8);
        #pragma unroll
        for (int j = 0; j < 16; ++j) {
            acc0[j] = fmaf(xa, wf[j], acc0[j]);
            acc1[j] = fmaf(xb, wf[j], acc1[j]);
        }
    }

    float* g0 = ckpt + (size_t)(k + 1) * CKPT_STRIDE + (size_t)r0 * HDIM + hc * 16;
    float* g1 = ckpt + (size_t)(k + 1) * CKPT_STRIDE + (size_t)r1 * HDIM + hc * 16;
    #pragma unroll
    for (int j = 0; j < 4; ++j) {
        *(float4*)(g0 + 4 * j) = make_float4(acc0[4*j+0], acc0[4*j+1], acc0[4*j+2], acc0[4*j+3]);
        *(float4*)(g1 + 4 * j) = make_float4(acc1[4*j+0], acc1[4*j+1], acc1[4*j+2], acc1[4*j+3]);
    }
}

// ---------------------------------------------------------------------------
// Pass 1.5: ckpt[0]=in_b ; ckpt[k] = ckpt[k-1] + G[k-1]
// ---------------------------------------------------------------------------
__global__ __launch_bounds__(256, 2)
void prefix_ck(const float* __restrict__ in_b, float* __restrict__ ckpt, int nseg) {
    int idx = blockIdx.x * 256 + threadIdx.x;
    int b  = idx >> 7;
    int hq = idx & 127;
    float* p = ckpt + (size_t)b * HDIM + hq * 4;
    float4 cur = *(const float4*)(in_b + hq * 4);
    *(float4*)p = cur;
    for (int k = 1; k < nseg; ++k) {
        float4 g = *(const float4*)(p + (size_t)k * CKPT_STRIDE);
        cur.x += g.x; cur.y += g.y; cur.z += g.z; cur.w += g.w;
        *(float4*)(p + (size_t)k * CKPT_STRIDE) = cur;
    }
}

// ---------------------------------------------------------------------------
// Pass 2: segment scan, bf16 staged weights.
// Block = 4 waves (256 thr); wave owns 4 batch rows. Lane l owns h=8l..8l+7.
// Prefetch issued AFTER the barrier (full-chunk latency cover).
// Single-pass LDS-transpose reduction: 16 outputs, 4 lanes each.
// __launch_bounds__ 2nd arg MUST be 2: arg=4 forces a 64-VGPR cap -> spill
// (R6: 550us, R9: 289us). arg=2 -> ~104 VGPR, no spill (R7).
// ---------------------------------------------------------------------------
__global__ __launch_bounds__(256, 2)
void nade_fwd6(const float* __restrict__ x,
               const float* __restrict__ ckpt,
               const ushort_t* __restrict__ hWb,
               const float* __restrict__ h_b,
               const ushort_t* __restrict__ wTb,
               float* __restrict__ out,
               int seglen, int nch) {
    __shared__ ushort_t sbuf[2][2][TC * HDIM];   // [buf][mat][2048] = 16 KB
    __shared__ float    sred[4][16 * 68];        // 17.4 KB

    const int tid = threadIdx.x;
    const int w   = tid >> 6;                    // wave 0..3
    const int l   = tid & 63;
    const int k   = blockIdx.y;
    const int base = k * seglen;
    const int row0 = blockIdx.x * 16 + w * 4;

    // accumulators from checkpoint k; lane owns h = 8l..8l+7
    float a[4][8];
    #pragma unroll
    for (int r = 0; r < 4; ++r) {
        const float* ap = ckpt + (size_t)k * CKPT_STRIDE + (size_t)(row0 + r) * HDIM + 8 * l;
        float4 a0 = *(const float4*)(ap);
        float4 a1 = *(const float4*)(ap + 4);
        a[r][0]=a0.x; a[r][1]=a0.y; a[r][2]=a0.z; a[r][3]=a0.w;
        a[r][4]=a1.x; a[r][5]=a1.y; a[r][6]=a1.z; a[r][7]=a1.w;
    }

    // x bitmasks (x exactly 0/1), wave-uniform
    unsigned long long lo0, lo1, lo2, lo3;
    unsigned long long hi0 = 0, hi1 = 0, hi2 = 0, hi3 = 0;
    {
        const float* xr0 = x + (size_t)(row0 + 0) * D_IN + base;
        const float* xr1 = x + (size_t)(row0 + 1) * D_IN + base;
        const float* xr2 = x + (size_t)(row0 + 2) * D_IN + base;
        const float* xr3 = x + (size_t)(row0 + 3) * D_IN + base;
        float v;
        v = (l < seglen) ? xr0[l] : 0.0f; lo0 = __ballot(v != 0.0f);
        v = (l < seglen) ? xr1[l] : 0.0f; lo1 = __ballot(v != 0.0f);
        v = (l < seglen) ? xr2[l] : 0.0f; lo2 = __ballot(v != 0.0f);
        v = (l < seglen) ? xr3[l] : 0.0f; lo3 = __ballot(v != 0.0f);
        if (seglen > 64) {
            v = (64 + l < seglen) ? xr0[64 + l] : 0.0f; hi0 = __ballot(v != 0.0f);
            v = (64 + l < seglen) ? xr1[64 + l] : 0.0f; hi1 = __ballot(v != 0.0f);
            v = (64 + l < seglen) ? xr2[64 + l] : 0.0f; hi2 = __ballot(v != 0.0f);
            v = (64 + l < seglen) ? xr3[64 + l] : 0.0f; hi3 = __ballot(v != 0.0f);
        }
    }

    // reduction/output geometry: output o = l>>2 -> row r=l>>4, t=(l>>2)&3
    const int tsel = (l >> 2) & 3;
    float* optr = out + (size_t)(row0 + (l >> 4)) * D_IN + base + tsel;

    // wave w stages mat m=w>>1, half hf=w&1 : 2 x 1KB global_load_lds issues
#define STAGE6(buf_, c_) {                                                                  \
        const int m_  = w >> 1;                                                             \
        const int hf_ = w & 1;                                                              \
        const ushort_t* src_ = (m_ ? wTb : hWb) + (size_t)(base + (c_) * TC) * HDIM         \
                               + hf_ * 1024 + l * 8;                                        \
        ushort_t* dst_ = &sbuf[buf_][m_][hf_ * 1024 + l * 8];                               \
        __builtin_amdgcn_global_load_lds(                                                   \
            (const __attribute__((address_space(1))) void*)(src_),                          \
            (__attribute__((address_space(3))) void*)(dst_), 16, 0, 0);                     \
        __builtin_amdgcn_global_load_lds(                                                   \
            (const __attribute__((address_space(1))) void*)(src_ + 512),                    \
            (__attribute__((address_space(3))) void*)(dst_ + 512), 16, 0, 0);               \
    }

    STAGE6(0, 0);
    if (nch > 1) STAGE6(1, 1);
    __syncthreads();    // drains both prologue stages

    for (int c = 0; c < nch; ++c) {
        const int buf = c & 1;
        const int sh = c * TC;
        const int s2 = sh & 63;
        const unsigned b0 = (unsigned)((((sh >= 64) ? hi0 : lo0) >> s2) & 15ull);
        const unsigned b1 = (unsigned)((((sh >= 64) ? hi1 : lo1) >> s2) & 15ull);
        const unsigned b2 = (unsigned)((((sh >= 64) ? hi2 : lo2) >> s2) & 15ull);
        const unsigned b3 = (unsigned)((((sh >= 64) ? hi3 : lo3) >> s2) & 15ull);
        const unsigned bu = b0 | b1 | b2 | b3;

        float4 hbc = *(const float4*)(h_b + base + sh);

        float part[4][4];
        #pragma unroll
        for (int t = 0; t < TC; ++t) {
            uint4 hv = *(const uint4*)&sbuf[buf][0][t * 512 + 8 * l];
            float hf[8];
            unpack8(hv, hf);
            #pragma unroll
            for (int r = 0; r < 4; ++r) {
                float p = relu_(a[r][0]) * hf[0];
                p = fmaf(relu_(a[r][1]), hf[1], p);
                p = fmaf(relu_(a[r][2]), hf[2], p);
                p = fmaf(relu_(a[r][3]), hf[3], p);
                p = fmaf(relu_(a[r][4]), hf[4], p);
                p = fmaf(relu_(a[r][5]), hf[5], p);
                p = fmaf(relu_(a[r][6]), hf[6], p);
                p = fmaf(relu_(a[r][7]), hf[7], p);
                part[r][t] = p;
            }

            const unsigned bt = 1u << t;
            if (bu & bt) {                 // wave-uniform
                uint4 wv = *(const uint4*)&sbuf[buf][1][t * 512 + 8 * l];
                float wf[8];
                unpack8(wv, wf);
                if (b0 & bt) {
                    a[0][0]+=wf[0]; a[0][1]+=wf[1]; a[0][2]+=wf[2]; a[0][3]+=wf[3];
                    a[0][4]+=wf[4]; a[0][5]+=wf[5]; a[0][6]+=wf[6]; a[0][7]+=wf[7];
                }
                if (b1 & bt) {
                    a[1][0]+=wf[0]; a[1][1]+=wf[1]; a[1][2]+=wf[2]; a[1][3]+=wf[3];
                    a[1][4]+=wf[4]; a[1][5]+=wf[5]; a[1][6]+=wf[6]; a[1][7]+=wf[7];
                }
                if (b2 & bt) {
                    a[2][0]+=wf[0]; a[2][1]+=wf[1]; a[2][2]+=wf[2]; a[2][3]+=wf[3];
                    a[2][4]+=wf[4]; a[2][5]+=wf[5]; a[2][6]+=wf[6]; a[2][7]+=wf[7];
                }
                if (b3 & bt) {
                    a[3][0]+=wf[0]; a[3][1]+=wf[1]; a[3][2]+=wf[2]; a[3][3]+=wf[3];
                    a[3][4]+=wf[4]; a[3][5]+=wf[5]; a[3][6]+=wf[6]; a[3][7]+=wf[7];
                }
            }
        }

        // single-pass reduction: 16 writes, 4 b128 reads, 2 narrow shfl
        #pragma unroll
        for (int r = 0; r < 4; ++r) {
            #pragma unroll
            for (int t = 0; t < TC; ++t)
                sred[w][(r * 4 + t) * 68 + l] = part[r][t];
        }

        const float* pr = &sred[w][(l >> 2) * 68 + (l & 3) * 16];
        float4 q0 = *(const float4*)(pr);
        float4 q1 = *(const float4*)(pr + 4);
        float4 q2 = *(const float4*)(pr + 8);
        float4 q3 = *(const float4*)(pr + 12);
        float v = (((q0.x + q0.y) + (q0.z + q0.w)) + ((q1.x + q1.y) + (q1.z + q1.w)))
                + (((q2.x + q2.y) + (q2.z + q2.w)) + ((q3.x + q3.y) + (q3.z + q3.w)));
        v += __shfl_xor(v, 1, 64);
        v += __shfl_xor(v, 2, 64);
        const float hbt = (tsel & 2) ? ((tsel & 1) ? hbc.w : hbc.z)
                                     : ((tsel & 1) ? hbc.y : hbc.x);
        float sv = sigmoid_(v + hbt);
        if ((l & 3) == 0) optr[sh] = sv;

        __syncthreads();
        if (c + 2 < nch) STAGE6(buf, c + 2);   // prefetch AFTER barrier: full-chunk cover
    }
#undef STAGE6
}

// ---------------------------------------------------------------------------
// Fallback (tiny ws): fp32, no workspace use
// ---------------------------------------------------------------------------
__global__ __launch_bounds__(64, 1)
void nade_fwd_fallback(const float* __restrict__ x,
                       const float* __restrict__ in_W,
                       const float* __restrict__ in_b,
                       const float* __restrict__ hW,
                       const float* __restrict__ h_b,
                       float* __restrict__ out) {
    const int b  = blockIdx.x;
    const int l  = threadIdx.x;
    const int h0 = l * 8;

    float a[8];
    {
        float4 b0 = *(const float4*)(in_b + h0);
        float4 b1 = *(const float4*)(in_b + h0 + 4);
        a[0]=b0.x; a[1]=b0.y; a[2]=b0.z; a[3]=b0.w;
        a[4]=b1.x; a[5]=b1.y; a[6]=b1.z; a[7]=b1.w;
    }
    const float* xrow = x + (size_t)b * D_IN;
    float* orow = out + (size_t)b * D_IN;

    for (int i = 0; i < D_IN; ++i) {
        const float4 hw0 = *(const float4*)(hW + (size_t)i * HDIM + h0);
        const float4 hw1 = *(const float4*)(hW + (size_t)i * HDIM + h0 + 4);
        float p;
        p = relu_(a[0]) * hw0.x;
        p = fmaf(relu_(a[1]), hw0.y, p);
        p = fmaf(relu_(a[2]), hw0.z, p);
        p = fmaf(relu_(a[3]), hw0.w, p);
        p = fmaf(relu_(a[4]), hw1.x, p);
        p = fmaf(relu_(a[5]), hw1.y, p);
        p = fmaf(relu_(a[6]), hw1.z, p);
        p = fmaf(relu_(a[7]), hw1.w, p);
        #pragma unroll
        for (int s = 1; s < 64; s <<= 1) p += __shfl_xor(p, s, 64);
        if (l == 0) orow[i] = sigmoid_(p + h_b[i]);

        const float xi = xrow[i];
        if (xi != 0.0f) {
            a[0] = fmaf(xi, in_W[(size_t)(h0+0)*D_IN + i], a[0]);
            a[1] = fmaf(xi, in_W[(size_t)(h0+1)*D_IN + i], a[1]);
            a[2] = fmaf(xi, in_W[(size_t)(h0+2)*D_IN + i], a[2]);
            a[3] = fmaf(xi, in_W[(size_t)(h0+3)*D_IN + i], a[3]);
            a[4] = fmaf(xi, in_W[(size_t)(h0+4)*D_IN + i], a[4]);
            a[5] = fmaf(xi, in_W[(size_t)(h0+5)*D_IN + i], a[5]);
            a[6] = fmaf(xi, in_W[(size_t)(h0+6)*D_IN + i], a[6]);
            a[7] = fmaf(xi, in_W[(size_t)(h0+7)*D_IN + i], a[7]);
        }
    }
}

extern "C" void kernel_launch(void* const* d_in, const int* in_sizes, int n_in,
                              void* d_out, int out_size, void* d_ws, size_t ws_size,
                              hipStream_t stream) {
    const float* x    = (const float*)d_in[0];
    const float* in_W = (const float*)d_in[1];
    const float* in_b = (const float*)d_in[2];
    const float* hW   = (const float*)d_in[3];
    const float* h_b  = (const float*)d_in[4];
    float* out = (float*)d_out;

    // ws layout: wTb (bf16) | hWb (bf16) | ckpt (fp32, nseg slots)
    const size_t bf_bytes = 2 * WT_FLOATS * sizeof(ushort_t);   // 1.6 MB
    int nseg = 0;
    const size_t need14 = bf_bytes + 14 * CKPT_STRIDE * sizeof(float);
    const size_t need7  = bf_bytes +  7 * CKPT_STRIDE * sizeof(float);
    if      (ws_size >= need14) nseg = 14;
    else if (ws_size >= need7)  nseg = 7;

    if (nseg) {
        const int seglen = D_IN / nseg;
        ushort_t* wTb = (ushort_t*)d_ws;
        ushort_t* hWb = wTb + WT_FLOATS;
        float*    ckpt = (float*)(hWb + WT_FLOATS);

        hipLaunchKernelGGL(cast_hW,
                           dim3((D_IN * HDIM + 255) / 256), dim3(256), 0, stream,
                           hW, hWb);
        hipLaunchKernelGGL(transpose_cast_inW,
                           dim3((D_IN + 31) / 32, HDIM / 32), dim3(256), 0, stream,
                           in_W, wTb);
        hipLaunchKernelGGL(seg_sums,
                           dim3(BATCH_N / 16, nseg - 1), dim3(256), 0, stream,
                           x, wTb, ckpt, seglen);
        hipLaunchKernelGGL(prefix_ck,
                           dim3(BATCH_N * (HDIM / 4) / 256), dim3(256), 0, stream,
                           in_b, ckpt, nseg);
        hipLaunchKernelGGL(nade_fwd6,
                           dim3(BATCH_N / 16, nseg), dim3(256), 0, stream,
                           x, ckpt, hWb, h_b, wTb, out, seglen, seglen / TC);
    } else {
        hipLaunchKernelGGL(nade_fwd_fallback,
                           dim3(BATCH_N), dim3(64), 0, stream,
                           x, in_W, in_b, hW, h_b, out);
    }
}